// Round 6
// baseline (210.985 us; speedup 1.0000x reference)
//
#include <hip/hip_runtime.h>

#define B_  2
#define T_  2048
#define D_  1024
#define H_  16
#define DH_ 64
#define M_  4096   // B*T

typedef _Float16 f16;
typedef _Float16 f16x8 __attribute__((ext_vector_type(8)));
typedef _Float16 f16x4 __attribute__((ext_vector_type(4)));
typedef float    f32x4  __attribute__((ext_vector_type(4)));
typedef float    f32x16 __attribute__((ext_vector_type(16)));
typedef unsigned int u32;

__device__ __forceinline__ void async_ld16(const void* g, void* l) {
  __builtin_amdgcn_global_load_lds(
      (const __attribute__((address_space(1))) unsigned int*)g,
      (__attribute__((address_space(3))) unsigned int*)l,
      16, 0, 0);
}

__device__ __forceinline__ u32 pkh(f16 a, f16 b) {
  union { f16 h[2]; u32 u; } x; x.h[0] = a; x.h[1] = b; return x.u;
}

// ---------------------------------------------------------------- convert ---
// blocks 0..8191: f32->f16 conversion.  blocks 8192..8193: per-batch padding
// length (dual-layout bool detector), written to lens_out[b].
__global__ __launch_bounds__(256) void convert_all(
    const float* __restrict__ q, const float* __restrict__ k, const float* __restrict__ v,
    const float* __restrict__ wq, const float* __restrict__ wk, const float* __restrict__ wv,
    const float* __restrict__ wo, const void* __restrict__ kpm_raw,
    f16* __restrict__ xh, f16* __restrict__ wh, int* __restrict__ lens_out) {
  int bid = blockIdx.x;
  if (bid >= 8192) {                // padding length for batch b
    int b = bid - 8192;
    __shared__ int s_c8, s_c32;
    if (threadIdx.x == 0) { s_c8 = 0; s_c32 = 0; }
    __syncthreads();
    int tid = threadIdx.x, lane = tid & 63;
    {
      const unsigned char* k8 = (const unsigned char*)kpm_raw + (long)b * T_;
      int cnt = 0;
      for (int j = tid; j < T_; j += 256) cnt += (k8[j] == 0) ? 1 : 0;
#pragma unroll
      for (int off = 1; off < 64; off <<= 1) cnt += __shfl_xor(cnt, off);
      if (lane == 0) atomicAdd(&s_c8, cnt);
    }
    {
      const int* k32 = (const int*)kpm_raw + (long)b * T_;
      int cnt = 0;
      for (int j = tid; j < T_; j += 256) cnt += (k32[j] == 0) ? 1 : 0;
#pragma unroll
      for (int off = 1; off < 64; off <<= 1) cnt += __shfl_xor(cnt, off);
      if (lane == 0) atomicAdd(&s_c32, cnt);
    }
    __syncthreads();
    if (tid == 0) lens_out[b] = (s_c8 == T_) ? s_c32 : s_c8;
    return;
  }
  const float* src;
  f16* dst;
  long base;
  if (bid < 6144) {                 // q,k,v : 3 x 4194304 elems, 2048 blocks each
    int r = bid >> 11;
    src = (r == 0) ? q : (r == 1) ? k : v;
    dst = xh + (long)r * 4194304;
    base = (long)(bid & 2047) * 2048;
  } else {                          // Wq,Wk,Wv,Wo : 4 x 1048576 elems, 512 blocks each
    int r = (bid - 6144) >> 9;
    src = (r == 0) ? wq : (r == 1) ? wk : (r == 2) ? wv : wo;
    dst = wh + (long)r * 1048576;
    base = (long)((bid - 6144) & 511) * 2048;
  }
  long e = base + (long)threadIdx.x * 8;
  const float4* s4 = (const float4*)(src + e);
  float4 f0 = s4[0], f1 = s4[1];
  f16x8 o;
  o[0] = (f16)f0.x; o[1] = (f16)f0.y; o[2] = (f16)f0.z; o[3] = (f16)f0.w;
  o[4] = (f16)f1.x; o[5] = (f16)f1.y; o[6] = (f16)f1.z; o[7] = (f16)f1.w;
  *(f16x8*)(dst + e) = o;
}

// ------------------------------------------------------------------- GEMM ---
// C = A(MxK) * W(NxK)^T.  M=4096, N=K=1024 for every GEMM in this problem.
// modes: 0 -> Qh (f16, *0.125)   1 -> Kh (f16)
//        2 -> Vt (f16, transposed per head [b,h,dh,t])   3 -> f32 out
__global__ __launch_bounds__(256) void gemm_k(
    const f16* __restrict__ Abase, const f16* __restrict__ Wbase,
    f16* __restrict__ Qb, f16* __restrict__ Kb, f16* __restrict__ Vt,
    float* __restrict__ Co, int which) {
  __shared__ __align__(16) f16 As[128][32];
  __shared__ __align__(16) f16 Bs[128][32];
  const int K = 1024, N = 1024;

  int mode;
  const f16 *A, *W;
  if (which) { mode = 3; A = Abase; W = Wbase; }
  else {
    mode = blockIdx.z;
    A = Abase + (long)blockIdx.z * 4194304;
    W = Wbase + (long)blockIdx.z * 1048576;
  }
  int m0 = blockIdx.y * 128, n0 = blockIdx.x * 128;
  int tid = threadIdx.x, lane = tid & 63, w = tid >> 6;
  int wm = w >> 1, wn = w & 1;

  const f16* pa = A + (long)(m0 + w * 16 + (lane >> 2)) * K + (lane & 3) * 8;
  const f16* pb = W + (long)(n0 + w * 16 + (lane >> 2)) * K + (lane & 3) * 8;
  f16* la = &As[w * 16 + (lane >> 2)][(lane & 3) * 8];
  f16* lb = &Bs[w * 16 + (lane >> 2)][(lane & 3) * 8];

  f32x4 acc[4][4] = {};
  int row = lane & 15, kq = (lane >> 4) * 8;

  for (int k0 = 0; k0 < K; k0 += 32) {
    async_ld16(pa + k0,          la);
    async_ld16(pa + 64 * K + k0, la + 64 * 32);
    async_ld16(pb + k0,          lb);
    async_ld16(pb + 64 * K + k0, lb + 64 * 32);
    __syncthreads();
    f16x8 af[4], bfr[4];
#pragma unroll
    for (int m = 0; m < 4; m++) af[m] = *(const f16x8*)&As[wm * 64 + m * 16 + row][kq];
#pragma unroll
    for (int n = 0; n < 4; n++) bfr[n] = *(const f16x8*)&Bs[wn * 64 + n * 16 + row][kq];
#pragma unroll
    for (int m = 0; m < 4; m++)
#pragma unroll
      for (int n = 0; n < 4; n++)
        acc[m][n] = __builtin_amdgcn_mfma_f32_16x16x32_f16(af[m], bfr[n], acc[m][n], 0, 0, 0);
    __syncthreads();
  }

  int r0 = (lane >> 4) * 4;
#pragma unroll
  for (int m = 0; m < 4; m++) {
    int gmb = m0 + wm * 64 + m * 16 + r0;
#pragma unroll
    for (int n = 0; n < 4; n++) {
      int gn = n0 + wn * 64 + n * 16 + row;
      if (mode == 0) {
#pragma unroll
        for (int i = 0; i < 4; i++)
          Qb[(long)(gmb + i) * N + gn] = (f16)(acc[m][n][i] * 0.125f);
      } else if (mode == 1) {
#pragma unroll
        for (int i = 0; i < 4; i++)
          Kb[(long)(gmb + i) * N + gn] = (f16)acc[m][n][i];
      } else if (mode == 2) {
        int b = gmb >> 11;
        int t = gmb & 2047;
        int h = gn >> 6, dh = gn & 63;
        f16x4 pk;
#pragma unroll
        for (int i = 0; i < 4; i++) pk[i] = (f16)acc[m][n][i];
        *(f16x4*)&Vt[(long)((b * 16 + h) * 64 + dh) * 2048 + t] = pk;
      } else {
#pragma unroll
        for (int i = 0; i < 4; i++)
          Co[(long)(gmb + i) * N + gn] = acc[m][n][i];
      }
    }
  }
}

// -------------------------------------------------------------- attention ---
// Split-K flash attention: 4 waves per 32-row q-tile, wave w takes k-tiles
// kb=(4t+w)*64 with private online softmax; partials merged via LDS.
struct KV64 {
  f16x8 kf[8];   // [tile(2)][dh-slice(4)]
  f16x8 vf[8];   // [dh-tile(2)][k-slice(4)]
};

__global__ __launch_bounds__(256) void attn_k(
    const f16* __restrict__ Q, const f16* __restrict__ Kp,
    const f16* __restrict__ Vt, const int* __restrict__ Lens,
    f16* __restrict__ Ao) {
  __shared__ float buf0[32][68];     // partial O (waves 0+2), dh 0..63, pad->68
  __shared__ float buf1[32][68];     // partial O (waves 1+3)
  __shared__ float mlds[4][32][2];   // per-wave per-row (m, l)

  int tid = threadIdx.x, lane = tid & 63, w = tid >> 6;
  int qt = (gridDim.x - 1) - blockIdx.x;   // longest-first
  int bh = blockIdx.y;
  int b = bh >> 4, h = bh & 15;
  int r31 = lane & 31, hi = lane >> 5, hi8 = hi * 8;

  int len = Lens[b];
  int q0 = qt * 32;
  int gq = q0 + r31;
  const f16* Qh = Q  + (long)b * T_ * D_ + h * 64;
  const f16* Kh = Kp + (long)b * T_ * D_ + h * 64;
  const f16* Vh = Vt + (long)(b * 16 + h) * 64 * T_;

  f16x8 qf[4];
#pragma unroll
  for (int t = 0; t < 4; t++)
    qf[t] = *(const f16x8*)(Qh + (long)gq * D_ + t * 16 + hi8);

  f32x16 o0 = {}, o1 = {};       // O^T partials: dh-tiles 0 (0..31), 1 (32..63)
  float mrun = -1e30f, lrun = 0.f;

  int kmax = (q0 + 32 < len) ? q0 + 32 : len;   // exclusive visible-key bound

  KV64 regA, regB;

  auto LOADKV = [&](KV64& t, int kb) {
    const f16* kp = Kh + ((long)kb + r31) * D_ + hi8;
#pragma unroll
    for (int tt = 0; tt < 2; tt++)
#pragma unroll
      for (int tq = 0; tq < 4; tq++)
        t.kf[tt * 4 + tq] = *(const f16x8*)(kp + tt * 32 * D_ + tq * 16);
    const f16* vp = Vh + (long)r31 * T_ + kb + hi8;
#pragma unroll
    for (int d = 0; d < 2; d++)
#pragma unroll
      for (int m = 0; m < 4; m++)
        t.vf[d * 4 + m] = *(const f16x8*)(vp + d * 32 * T_ + m * 16);
  };

  auto PROC = [&](KV64& t, int kb) {
    f32x16 s0 = {}, s1 = {};
#pragma unroll
    for (int tq = 0; tq < 4; tq++) {
      s0 = __builtin_amdgcn_mfma_f32_32x32x16_f16(t.kf[tq],     qf[tq], s0, 0, 0, 0);
      s1 = __builtin_amdgcn_mfma_f32_32x32x16_f16(t.kf[4 + tq], qf[tq], s1, 0, 0, 0);
    }

    bool needmask = (kb + 64 > q0) || (kb + 64 > len);
    float sv[32];
    if (needmask) {
#pragma unroll
      for (int r = 0; r < 16; r++) {
        int pat = (r & 3) + 8 * (r >> 2) + 4 * hi;
        int gk0 = kb + pat, gk1 = kb + 32 + pat;
        sv[r]      = (gk0 > gq || gk0 >= len) ? -1e30f : s0[r];
        sv[16 + r] = (gk1 > gq || gk1 >= len) ? -1e30f : s1[r];
      }
    } else {
#pragma unroll
      for (int r = 0; r < 16; r++) { sv[r] = s0[r]; sv[16 + r] = s1[r]; }
    }

    float mx = fmaxf(sv[0], sv[1]);
#pragma unroll
    for (int r = 2; r < 32; r++) mx = fmaxf(mx, sv[r]);
    mx = fmaxf(mx, __shfl_xor(mx, 32));

    float mnew = fmaxf(mrun, mx);
    float sf = __expf(mrun - mnew);
    mrun = mnew;

    f16 p16[32];
    float ps[4] = {0.f, 0.f, 0.f, 0.f};
#pragma unroll
    for (int r = 0; r < 32; r++) {
      float p = __expf(sv[r] - mnew);
      f16 hp = (f16)p;
      p16[r] = hp;
      ps[r & 3] += (float)hp;    // denominator from the SAME rounded weights
    }
    float psum = (ps[0] + ps[1]) + (ps[2] + ps[3]);
    lrun = lrun * sf + psum + __shfl_xor(psum, 32);

    o0 *= sf;
    o1 *= sf;

    u32 A0 = pkh(p16[0],  p16[1]),  A1 = pkh(p16[2],  p16[3]);
    u32 B0 = pkh(p16[4],  p16[5]),  B1 = pkh(p16[6],  p16[7]);
    u32 C0 = pkh(p16[8],  p16[9]),  C1 = pkh(p16[10], p16[11]);
    u32 D0 = pkh(p16[12], p16[13]), D1 = pkh(p16[14], p16[15]);
    u32 E0 = pkh(p16[16], p16[17]), E1 = pkh(p16[18], p16[19]);
    u32 F0 = pkh(p16[20], p16[21]), F1 = pkh(p16[22], p16[23]);
    u32 G0 = pkh(p16[24], p16[25]), G1 = pkh(p16[26], p16[27]);
    u32 H0 = pkh(p16[28], p16[29]), H1 = pkh(p16[30], p16[31]);
    u32 sA0 = __shfl_xor(A0, 32), sA1 = __shfl_xor(A1, 32);
    u32 sB0 = __shfl_xor(B0, 32), sB1 = __shfl_xor(B1, 32);
    u32 sC0 = __shfl_xor(C0, 32), sC1 = __shfl_xor(C1, 32);
    u32 sD0 = __shfl_xor(D0, 32), sD1 = __shfl_xor(D1, 32);
    u32 sE0 = __shfl_xor(E0, 32), sE1 = __shfl_xor(E1, 32);
    u32 sF0 = __shfl_xor(F0, 32), sF1 = __shfl_xor(F1, 32);
    u32 sG0 = __shfl_xor(G0, 32), sG1 = __shfl_xor(G1, 32);
    u32 sH0 = __shfl_xor(H0, 32), sH1 = __shfl_xor(H1, 32);

    union { u32 w[4]; f16x8 v; } f00, f01, f10, f11;
    f00.w[0] = hi ? sB0 : A0;  f00.w[1] = hi ? sB1 : A1;
    f00.w[2] = hi ? B0 : sA0;  f00.w[3] = hi ? B1 : sA1;
    f01.w[0] = hi ? sD0 : C0;  f01.w[1] = hi ? sD1 : C1;
    f01.w[2] = hi ? D0 : sC0;  f01.w[3] = hi ? D1 : sC1;
    f10.w[0] = hi ? sF0 : E0;  f10.w[1] = hi ? sF1 : E1;
    f10.w[2] = hi ? F0 : sE0;  f10.w[3] = hi ? F1 : sE1;
    f11.w[0] = hi ? sH0 : G0;  f11.w[1] = hi ? sH1 : G1;
    f11.w[2] = hi ? H0 : sG0;  f11.w[3] = hi ? H1 : sG1;

    o0 = __builtin_amdgcn_mfma_f32_32x32x16_f16(t.vf[0], f00.v, o0, 0, 0, 0);
    o0 = __builtin_amdgcn_mfma_f32_32x32x16_f16(t.vf[1], f01.v, o0, 0, 0, 0);
    o0 = __builtin_amdgcn_mfma_f32_32x32x16_f16(t.vf[2], f10.v, o0, 0, 0, 0);
    o0 = __builtin_amdgcn_mfma_f32_32x32x16_f16(t.vf[3], f11.v, o0, 0, 0, 0);
    o1 = __builtin_amdgcn_mfma_f32_32x32x16_f16(t.vf[4], f00.v, o1, 0, 0, 0);
    o1 = __builtin_amdgcn_mfma_f32_32x32x16_f16(t.vf[5], f01.v, o1, 0, 0, 0);
    o1 = __builtin_amdgcn_mfma_f32_32x32x16_f16(t.vf[6], f10.v, o1, 0, 0, 0);
    o1 = __builtin_amdgcn_mfma_f32_32x32x16_f16(t.vf[7], f11.v, o1, 0, 0, 0);
  };

  // this wave's strided k-tiles: kb = w*64, w*64+256, ...
  int kb = w * 64;
  if (kb < kmax) {
    LOADKV(regA, kb);
    while (true) {
      if (kb + 256 < kmax) LOADKV(regB, kb + 256);
      PROC(regA, kb);
      kb += 256;
      if (kb >= kmax) break;
      if (kb + 256 < kmax) LOADKV(regA, kb + 256);
      PROC(regB, kb);
      kb += 256;
      if (kb >= kmax) break;
    }
  }

  // ---- merge 4 wave-partials -------------------------------------------
  if (hi == 0) { mlds[w][r31][0] = mrun; mlds[w][r31][1] = lrun; }
  __syncthreads();

  float mstar = fmaxf(fmaxf(mlds[0][r31][0], mlds[1][r31][0]),
                      fmaxf(mlds[2][r31][0], mlds[3][r31][0]));
  float cw = __expf(mrun - mstar);   // 0 for zero-tile waves
  o0 *= cw;
  o1 *= cw;

  float (*mybuf)[68] = (w & 1) ? buf1 : buf0;
  if (w < 2) {
#pragma unroll
    for (int g = 0; g < 4; g++) {
      f32x4 a, c;
#pragma unroll
      for (int i = 0; i < 4; i++) { a[i] = o0[g * 4 + i]; c[i] = o1[g * 4 + i]; }
      *(f32x4*)&mybuf[r31][8 * g + 4 * hi]      = a;
      *(f32x4*)&mybuf[r31][32 + 8 * g + 4 * hi] = c;
    }
  }
  __syncthreads();
  if (w >= 2) {
#pragma unroll
    for (int g = 0; g < 4; g++) {
      f32x4 a = *(f32x4*)&mybuf[r31][8 * g + 4 * hi];
      f32x4 c = *(f32x4*)&mybuf[r31][32 + 8 * g + 4 * hi];
#pragma unroll
      for (int i = 0; i < 4; i++) { a[i] += o0[g * 4 + i]; c[i] += o1[g * 4 + i]; }
      *(f32x4*)&mybuf[r31][8 * g + 4 * hi]      = a;
      *(f32x4*)&mybuf[r31][32 + 8 * g + 4 * hi] = c;
    }
  }
  __syncthreads();

  // ---- normalize + write out: wave w -> rows [8w, 8w+8) ------------------
  int row = w * 8 + (lane >> 3);
  int dh0 = (lane & 7) * 8;
  float m0r = mlds[0][row][0], m1r = mlds[1][row][0];
  float m2r = mlds[2][row][0], m3r = mlds[3][row][0];
  float msr = fmaxf(fmaxf(m0r, m1r), fmaxf(m2r, m3r));
  float lst = __expf(m0r - msr) * mlds[0][row][1] + __expf(m1r - msr) * mlds[1][row][1]
            + __expf(m2r - msr) * mlds[2][row][1] + __expf(m3r - msr) * mlds[3][row][1];
  float linv = 1.f / lst;

  f32x4 a0 = *(f32x4*)&buf0[row][dh0],     a1 = *(f32x4*)&buf0[row][dh0 + 4];
  f32x4 b0 = *(f32x4*)&buf1[row][dh0],     b1 = *(f32x4*)&buf1[row][dh0 + 4];
  f16x8 outv;
#pragma unroll
  for (int i = 0; i < 4; i++) {
    outv[i]     = (f16)((a0[i] + b0[i]) * linv);
    outv[4 + i] = (f16)((a1[i] + b1[i]) * linv);
  }
  *(f16x8*)(Ao + (long)(b * T_ + q0 + row) * D_ + h * 64 + dh0) = outv;
}

// ------------------------------------------------------------------ launch ---
extern "C" void kernel_launch(void* const* d_in, const int* in_sizes, int n_in,
                              void* d_out, int out_size, void* d_ws, size_t ws_size,
                              hipStream_t stream) {
  const float* q  = (const float*)d_in[0];
  const float* k  = (const float*)d_in[1];
  const float* v  = (const float*)d_in[2];
  // d_in[3] = causal mask (analytic, unused)
  const void* kpm = d_in[4];
  const float* wq = (const float*)d_in[5];
  const float* wk = (const float*)d_in[6];
  const float* wv = (const float*)d_in[7];
  const float* wo = (const float*)d_in[8];

  char* ws = (char*)d_ws;
  f16* Xh = (f16*)(ws);                     // 3 * 8 MB
  f16* Wh = (f16*)(ws + 25165824);          // 4 * 2 MB
  f16* Qb = (f16*)(ws + 33554432);          // 8 MB
  f16* Kb = (f16*)(ws + 41943040);          // 8 MB
  f16* Vt = (f16*)(ws + 50331648);          // 8 MB
  f16* Ao = (f16*)(ws + 58720256);          // 8 MB  (total 64 MB)
  // Lens scratch: first 2 ints of d_out — read by attn, then fully
  // overwritten by the final GEMM.
  int* Lens = (int*)d_out;

  convert_all<<<8194, 256, 0, stream>>>(q, k, v, wq, wk, wv, wo, kpm, Xh, Wh, Lens);

  gemm_k<<<dim3(8, 32, 3), 256, 0, stream>>>(Xh, Wh, Qb, Kb, Vt, nullptr, 0);

  attn_k<<<dim3(T_ / 32, B_ * H_), 256, 0, stream>>>(Qb, Kb, Vt, Lens, Ao);

  gemm_k<<<dim3(8, 32, 1), 256, 0, stream>>>(Ao, Wh + 3 * 1048576, nullptr, nullptr,
                                             nullptr, (float*)d_out, 1);
}

// Round 7
// 160.598 us; speedup vs baseline: 1.3137x; 1.3137x over previous
//
#include <hip/hip_runtime.h>

#define B_  2
#define T_  2048
#define D_  1024
#define H_  16
#define DH_ 64
#define M_  4096   // B*T

typedef _Float16 f16;
typedef _Float16 f16x8 __attribute__((ext_vector_type(8)));
typedef _Float16 f16x4 __attribute__((ext_vector_type(4)));
typedef float    f32x4  __attribute__((ext_vector_type(4)));
typedef float    f32x16 __attribute__((ext_vector_type(16)));
typedef unsigned int u32;

__device__ __forceinline__ void async_ld16(const void* g, void* l) {
  __builtin_amdgcn_global_load_lds(
      (const __attribute__((address_space(1))) unsigned int*)g,
      (__attribute__((address_space(3))) unsigned int*)l,
      16, 0, 0);
}

__device__ __forceinline__ u32 pkh(f16 a, f16 b) {
  union { f16 h[2]; u32 u; } x; x.h[0] = a; x.h[1] = b; return x.u;
}

// ---------------------------------------------------------------- convert ---
// blocks 0..8191: f32->f16 conversion.  blocks 8192..8193: per-batch padding
// length (dual-layout bool detector), written to lens_out[b].
__global__ __launch_bounds__(256) void convert_all(
    const float* __restrict__ q, const float* __restrict__ k, const float* __restrict__ v,
    const float* __restrict__ wq, const float* __restrict__ wk, const float* __restrict__ wv,
    const float* __restrict__ wo, const void* __restrict__ kpm_raw,
    f16* __restrict__ xh, f16* __restrict__ wh, int* __restrict__ lens_out) {
  int bid = blockIdx.x;
  if (bid >= 8192) {                // padding length for batch b
    int b = bid - 8192;
    __shared__ int s_c8, s_c32;
    if (threadIdx.x == 0) { s_c8 = 0; s_c32 = 0; }
    __syncthreads();
    int tid = threadIdx.x, lane = tid & 63;
    {
      const unsigned char* k8 = (const unsigned char*)kpm_raw + (long)b * T_;
      int cnt = 0;
      for (int j = tid; j < T_; j += 256) cnt += (k8[j] == 0) ? 1 : 0;
#pragma unroll
      for (int off = 1; off < 64; off <<= 1) cnt += __shfl_xor(cnt, off);
      if (lane == 0) atomicAdd(&s_c8, cnt);
    }
    {
      const int* k32 = (const int*)kpm_raw + (long)b * T_;
      int cnt = 0;
      for (int j = tid; j < T_; j += 256) cnt += (k32[j] == 0) ? 1 : 0;
#pragma unroll
      for (int off = 1; off < 64; off <<= 1) cnt += __shfl_xor(cnt, off);
      if (lane == 0) atomicAdd(&s_c32, cnt);
    }
    __syncthreads();
    if (tid == 0) lens_out[b] = (s_c8 == T_) ? s_c32 : s_c8;
    return;
  }
  const float* src;
  f16* dst;
  long base;
  if (bid < 6144) {                 // q,k,v : 3 x 4194304 elems, 2048 blocks each
    int r = bid >> 11;
    src = (r == 0) ? q : (r == 1) ? k : v;
    dst = xh + (long)r * 4194304;
    base = (long)(bid & 2047) * 2048;
  } else {                          // Wq,Wk,Wv,Wo : 4 x 1048576 elems, 512 blocks each
    int r = (bid - 6144) >> 9;
    src = (r == 0) ? wq : (r == 1) ? wk : (r == 2) ? wv : wo;
    dst = wh + (long)r * 1048576;
    base = (long)((bid - 6144) & 511) * 2048;
  }
  long e = base + (long)threadIdx.x * 8;
  const float4* s4 = (const float4*)(src + e);
  float4 f0 = s4[0], f1 = s4[1];
  f16x8 o;
  o[0] = (f16)f0.x; o[1] = (f16)f0.y; o[2] = (f16)f0.z; o[3] = (f16)f0.w;
  o[4] = (f16)f1.x; o[5] = (f16)f1.y; o[6] = (f16)f1.z; o[7] = (f16)f1.w;
  *(f16x8*)(dst + e) = o;
}

// ------------------------------------------------------------------- GEMM ---
// C = A(MxK) * W(NxK)^T.  M=4096, N=K=1024 for every GEMM in this problem.
// modes: 0 -> Qh (f16, *0.125)   1 -> Kh (f16)
//        2 -> Vt (f16, transposed per head [b,h,dh,t])   3 -> f32 out
__global__ __launch_bounds__(256) void gemm_k(
    const f16* __restrict__ Abase, const f16* __restrict__ Wbase,
    f16* __restrict__ Qb, f16* __restrict__ Kb, f16* __restrict__ Vt,
    float* __restrict__ Co, int which) {
  __shared__ __align__(16) f16 As[128][32];
  __shared__ __align__(16) f16 Bs[128][32];
  const int K = 1024, N = 1024;

  int mode;
  const f16 *A, *W;
  if (which) { mode = 3; A = Abase; W = Wbase; }
  else {
    mode = blockIdx.z;
    A = Abase + (long)blockIdx.z * 4194304;
    W = Wbase + (long)blockIdx.z * 1048576;
  }
  int m0 = blockIdx.y * 128, n0 = blockIdx.x * 128;
  int tid = threadIdx.x, lane = tid & 63, w = tid >> 6;
  int wm = w >> 1, wn = w & 1;

  const f16* pa = A + (long)(m0 + w * 16 + (lane >> 2)) * K + (lane & 3) * 8;
  const f16* pb = W + (long)(n0 + w * 16 + (lane >> 2)) * K + (lane & 3) * 8;
  f16* la = &As[w * 16 + (lane >> 2)][(lane & 3) * 8];
  f16* lb = &Bs[w * 16 + (lane >> 2)][(lane & 3) * 8];

  f32x4 acc[4][4] = {};
  int row = lane & 15, kq = (lane >> 4) * 8;

  for (int k0 = 0; k0 < K; k0 += 32) {
    async_ld16(pa + k0,          la);
    async_ld16(pa + 64 * K + k0, la + 64 * 32);
    async_ld16(pb + k0,          lb);
    async_ld16(pb + 64 * K + k0, lb + 64 * 32);
    __syncthreads();
    f16x8 af[4], bfr[4];
#pragma unroll
    for (int m = 0; m < 4; m++) af[m] = *(const f16x8*)&As[wm * 64 + m * 16 + row][kq];
#pragma unroll
    for (int n = 0; n < 4; n++) bfr[n] = *(const f16x8*)&Bs[wn * 64 + n * 16 + row][kq];
#pragma unroll
    for (int m = 0; m < 4; m++)
#pragma unroll
      for (int n = 0; n < 4; n++)
        acc[m][n] = __builtin_amdgcn_mfma_f32_16x16x32_f16(af[m], bfr[n], acc[m][n], 0, 0, 0);
    __syncthreads();
  }

  int r0 = (lane >> 4) * 4;
#pragma unroll
  for (int m = 0; m < 4; m++) {
    int gmb = m0 + wm * 64 + m * 16 + r0;
#pragma unroll
    for (int n = 0; n < 4; n++) {
      int gn = n0 + wn * 64 + n * 16 + row;
      if (mode == 0) {
#pragma unroll
        for (int i = 0; i < 4; i++)
          Qb[(long)(gmb + i) * N + gn] = (f16)(acc[m][n][i] * 0.125f);
      } else if (mode == 1) {
#pragma unroll
        for (int i = 0; i < 4; i++)
          Kb[(long)(gmb + i) * N + gn] = (f16)acc[m][n][i];
      } else if (mode == 2) {
        int b = gmb >> 11;
        int t = gmb & 2047;
        int h = gn >> 6, dh = gn & 63;
        f16x4 pk;
#pragma unroll
        for (int i = 0; i < 4; i++) pk[i] = (f16)acc[m][n][i];
        *(f16x4*)&Vt[(long)((b * 16 + h) * 64 + dh) * 2048 + t] = pk;
      } else {
#pragma unroll
        for (int i = 0; i < 4; i++)
          Co[(long)(gmb + i) * N + gn] = acc[m][n][i];
      }
    }
  }
}

// -------------------------------------------------------------- attention ---
// LDS-staged flash attention. Block = 4 waves = 128 q-rows (wave w owns 32).
// K[64][64] and V^T[64][64] tiles double-buffered in LDS, staged with
// global_load_lds (linear dest, XOR-swizzled global source so swizzled
// ds_read_b128 fragment reads are bank-conflict-free).
__global__ __launch_bounds__(256) void attn_k(
    const f16* __restrict__ Q, const f16* __restrict__ Kp,
    const f16* __restrict__ Vt, const int* __restrict__ Lens,
    f16* __restrict__ Ao) {
  __shared__ __align__(16) f16 Kl[2][4096];   // [buf][row*64 + chunk-swizzled]
  __shared__ __align__(16) f16 Vl[2][4096];   // [buf][dh*64 + chunk-swizzled]

  int tid = threadIdx.x, lane = tid & 63, w = tid >> 6;
  int qm = (gridDim.x - 1) - blockIdx.x;   // longest-first
  int bh = blockIdx.y;
  int b = bh >> 4, h = bh & 15;
  int r31 = lane & 31, hi = lane >> 5, hi8 = hi * 8;

  int len = Lens[b];
  int q0 = qm * 128;
  int q0w = q0 + w * 32;
  int gq = q0w + r31;

  int blk_kmax = min(q0 + 128, len);       // block-level visible keys
  int wav_kmax = min(q0w + 32, len);       // this wave's visible keys
  int NT = (blk_kmax + 63) >> 6;           // block-uniform tile count

  const f16* Qh = Q  + (long)b * T_ * D_ + h * 64;
  const f16* Kh = Kp + (long)b * T_ * D_ + h * 64;
  const f16* Vh = Vt + (long)(b * 16 + h) * 64 * T_;

  // stage-source constants: thread covers rows srow, srow+8 (shot s), chunk sc
  int srow = w * 16 + (lane >> 3);
  int sc8  = ((lane & 7) ^ ((lane >> 3) & 7)) * 8;   // swizzled 16B-chunk, f16 elems
  int ldst = w * 1024 + lane * 8;                    // f16 elems; +512 for shot 1

  // reader swizzled chunk offsets (constant per lane): logical chunk 2t+hi
  int coff[4];
#pragma unroll
  for (int t = 0; t < 4; t++) coff[t] = ((2 * t + hi) ^ (r31 & 7)) * 8;

  auto STAGE = [&](int t, int bsel) {
    int kb = t * 64;
#pragma unroll
    for (int s = 0; s < 2; s++) {
      int row = srow + s * 8;
      async_ld16(Kh + (long)(kb + row) * D_ + sc8, &Kl[bsel][ldst + s * 512]);
      async_ld16(Vh + (long)row * T_ + kb + sc8,   &Vl[bsel][ldst + s * 512]);
    }
  };

  // Q fragments: lane holds Q[gq][16t + hi*8 .. +8]
  STAGE(0, 0);
  f16x8 qf[4];
#pragma unroll
  for (int t = 0; t < 4; t++)
    qf[t] = *(const f16x8*)(Qh + (long)gq * D_ + t * 16 + hi8);

  f32x16 o0 = {}, o1 = {};       // O^T partials: dh-tiles 0 (0..31), 1 (32..63)
  float mrun = -1e30f, lrun = 0.f;

  asm volatile("s_waitcnt vmcnt(0)" ::: "memory");
  __syncthreads();

  for (int t = 0; t < NT; t++) {
    int cur = t & 1;
    if (t + 1 < NT) STAGE(t + 1, cur ^ 1);

    int kb = t * 64;
    if (kb < wav_kmax) {
      f32x16 s0 = {}, s1 = {};
#pragma unroll
      for (int tq = 0; tq < 4; tq++) {
        f16x8 k0 = *(const f16x8*)&Kl[cur][(r31)      * 64 + coff[tq]];
        f16x8 k1 = *(const f16x8*)&Kl[cur][(32 + r31) * 64 + coff[tq]];
        s0 = __builtin_amdgcn_mfma_f32_32x32x16_f16(k0, qf[tq], s0, 0, 0, 0);
        s1 = __builtin_amdgcn_mfma_f32_32x32x16_f16(k1, qf[tq], s1, 0, 0, 0);
      }

      bool needmask = (kb + 64 > q0w) || (kb + 64 > len);
      float sv[32];
      if (needmask) {
#pragma unroll
        for (int r = 0; r < 16; r++) {
          int pat = (r & 3) + 8 * (r >> 2) + 4 * hi;
          int gk0 = kb + pat, gk1 = kb + 32 + pat;
          sv[r]      = (gk0 > gq || gk0 >= len) ? -1e30f : s0[r];
          sv[16 + r] = (gk1 > gq || gk1 >= len) ? -1e30f : s1[r];
        }
      } else {
#pragma unroll
        for (int r = 0; r < 16; r++) { sv[r] = s0[r]; sv[16 + r] = s1[r]; }
      }

      float mx = fmaxf(sv[0], sv[1]);
#pragma unroll
      for (int r = 2; r < 32; r++) mx = fmaxf(mx, sv[r]);
      mx = fmaxf(mx, __shfl_xor(mx, 32));

      float mnew = fmaxf(mrun, mx);
      float sf = __expf(mrun - mnew);
      mrun = mnew;

      f16 p16[32];
      float ps[4] = {0.f, 0.f, 0.f, 0.f};
#pragma unroll
      for (int r = 0; r < 32; r++) {
        float p = __expf(sv[r] - mnew);
        f16 hp = (f16)p;
        p16[r] = hp;
        ps[r & 3] += (float)hp;    // denominator from the SAME rounded weights
      }
      float psum = (ps[0] + ps[1]) + (ps[2] + ps[3]);
      lrun = lrun * sf + psum + __shfl_xor(psum, 32);

      o0 *= sf;
      o1 *= sf;

      u32 A0 = pkh(p16[0],  p16[1]),  A1 = pkh(p16[2],  p16[3]);
      u32 B0 = pkh(p16[4],  p16[5]),  B1 = pkh(p16[6],  p16[7]);
      u32 C0 = pkh(p16[8],  p16[9]),  C1 = pkh(p16[10], p16[11]);
      u32 D0 = pkh(p16[12], p16[13]), D1 = pkh(p16[14], p16[15]);
      u32 E0 = pkh(p16[16], p16[17]), E1 = pkh(p16[18], p16[19]);
      u32 F0 = pkh(p16[20], p16[21]), F1 = pkh(p16[22], p16[23]);
      u32 G0 = pkh(p16[24], p16[25]), G1 = pkh(p16[26], p16[27]);
      u32 H0 = pkh(p16[28], p16[29]), H1 = pkh(p16[30], p16[31]);
      u32 sA0 = __shfl_xor(A0, 32), sA1 = __shfl_xor(A1, 32);
      u32 sB0 = __shfl_xor(B0, 32), sB1 = __shfl_xor(B1, 32);
      u32 sC0 = __shfl_xor(C0, 32), sC1 = __shfl_xor(C1, 32);
      u32 sD0 = __shfl_xor(D0, 32), sD1 = __shfl_xor(D1, 32);
      u32 sE0 = __shfl_xor(E0, 32), sE1 = __shfl_xor(E1, 32);
      u32 sF0 = __shfl_xor(F0, 32), sF1 = __shfl_xor(F1, 32);
      u32 sG0 = __shfl_xor(G0, 32), sG1 = __shfl_xor(G1, 32);
      u32 sH0 = __shfl_xor(H0, 32), sH1 = __shfl_xor(H1, 32);

      union { u32 w[4]; f16x8 v; } f00, f01, f10, f11;
      f00.w[0] = hi ? sB0 : A0;  f00.w[1] = hi ? sB1 : A1;
      f00.w[2] = hi ? B0 : sA0;  f00.w[3] = hi ? B1 : sA1;
      f01.w[0] = hi ? sD0 : C0;  f01.w[1] = hi ? sD1 : C1;
      f01.w[2] = hi ? D0 : sC0;  f01.w[3] = hi ? D1 : sC1;
      f10.w[0] = hi ? sF0 : E0;  f10.w[1] = hi ? sF1 : E1;
      f10.w[2] = hi ? F0 : sE0;  f10.w[3] = hi ? F1 : sE1;
      f11.w[0] = hi ? sH0 : G0;  f11.w[1] = hi ? sH1 : G1;
      f11.w[2] = hi ? H0 : sG0;  f11.w[3] = hi ? H1 : sG1;

      f16x8 v00 = *(const f16x8*)&Vl[cur][(r31)      * 64 + coff[0]];
      f16x8 v01 = *(const f16x8*)&Vl[cur][(r31)      * 64 + coff[1]];
      f16x8 v02 = *(const f16x8*)&Vl[cur][(r31)      * 64 + coff[2]];
      f16x8 v03 = *(const f16x8*)&Vl[cur][(r31)      * 64 + coff[3]];
      f16x8 v10 = *(const f16x8*)&Vl[cur][(32 + r31) * 64 + coff[0]];
      f16x8 v11 = *(const f16x8*)&Vl[cur][(32 + r31) * 64 + coff[1]];
      f16x8 v12 = *(const f16x8*)&Vl[cur][(32 + r31) * 64 + coff[2]];
      f16x8 v13 = *(const f16x8*)&Vl[cur][(32 + r31) * 64 + coff[3]];

      o0 = __builtin_amdgcn_mfma_f32_32x32x16_f16(v00, f00.v, o0, 0, 0, 0);
      o0 = __builtin_amdgcn_mfma_f32_32x32x16_f16(v01, f01.v, o0, 0, 0, 0);
      o0 = __builtin_amdgcn_mfma_f32_32x32x16_f16(v02, f10.v, o0, 0, 0, 0);
      o0 = __builtin_amdgcn_mfma_f32_32x32x16_f16(v03, f11.v, o0, 0, 0, 0);
      o1 = __builtin_amdgcn_mfma_f32_32x32x16_f16(v10, f00.v, o1, 0, 0, 0);
      o1 = __builtin_amdgcn_mfma_f32_32x32x16_f16(v11, f01.v, o1, 0, 0, 0);
      o1 = __builtin_amdgcn_mfma_f32_32x32x16_f16(v12, f10.v, o1, 0, 0, 0);
      o1 = __builtin_amdgcn_mfma_f32_32x32x16_f16(v13, f11.v, o1, 0, 0, 0);
    }

    asm volatile("s_waitcnt vmcnt(0)" ::: "memory");
    __syncthreads();
  }

  float linv = 1.f / lrun;
  f16* Aob = Ao + (long)(b * T_ + gq) * D_ + h * 64 + 4 * hi;
#pragma unroll
  for (int g = 0; g < 4; g++) {
    f16x4 s0, s1;
#pragma unroll
    for (int i = 0; i < 4; i++) {
      s0[i] = (f16)(o0[g * 4 + i] * linv);
      s1[i] = (f16)(o1[g * 4 + i] * linv);
    }
    *(f16x4*)(Aob + 8 * g)      = s0;
    *(f16x4*)(Aob + 32 + 8 * g) = s1;
  }
}

// ------------------------------------------------------------------ launch ---
extern "C" void kernel_launch(void* const* d_in, const int* in_sizes, int n_in,
                              void* d_out, int out_size, void* d_ws, size_t ws_size,
                              hipStream_t stream) {
  const float* q  = (const float*)d_in[0];
  const float* k  = (const float*)d_in[1];
  const float* v  = (const float*)d_in[2];
  // d_in[3] = causal mask (analytic, unused)
  const void* kpm = d_in[4];
  const float* wq = (const float*)d_in[5];
  const float* wk = (const float*)d_in[6];
  const float* wv = (const float*)d_in[7];
  const float* wo = (const float*)d_in[8];

  char* ws = (char*)d_ws;
  f16* Xh = (f16*)(ws);                     // 3 * 8 MB
  f16* Wh = (f16*)(ws + 25165824);          // 4 * 2 MB
  f16* Qb = (f16*)(ws + 33554432);          // 8 MB
  f16* Kb = (f16*)(ws + 41943040);          // 8 MB
  f16* Vt = (f16*)(ws + 50331648);          // 8 MB
  f16* Ao = (f16*)(ws + 58720256);          // 8 MB  (total 64 MB)
  // Lens scratch: first 2 ints of d_out — read by attn, then fully
  // overwritten by the final GEMM.
  int* Lens = (int*)d_out;

  convert_all<<<8194, 256, 0, stream>>>(q, k, v, wq, wk, wv, wo, kpm, Xh, Wh, Lens);

  gemm_k<<<dim3(8, 32, 3), 256, 0, stream>>>(Xh, Wh, Qb, Kb, Vt, nullptr, 0);

  attn_k<<<dim3(T_ / 128, B_ * H_), 256, 0, stream>>>(Qb, Kb, Vt, Lens, Ao);

  gemm_k<<<dim3(8, 32, 1), 256, 0, stream>>>(Ao, Wh + 3 * 1048576, nullptr, nullptr,
                                             nullptr, (float*)d_out, 1);
}

// Round 8
// 139.616 us; speedup vs baseline: 1.5112x; 1.1503x over previous
//
#include <hip/hip_runtime.h>

#define B_  2
#define T_  2048
#define D_  1024
#define H_  16
#define DH_ 64
#define M_  4096   // B*T

typedef _Float16 f16;
typedef _Float16 f16x8 __attribute__((ext_vector_type(8)));
typedef _Float16 f16x4 __attribute__((ext_vector_type(4)));
typedef float    f32x4  __attribute__((ext_vector_type(4)));
typedef float    f32x16 __attribute__((ext_vector_type(16)));
typedef unsigned int u32;

__device__ __forceinline__ void async_ld16(const void* g, void* l) {
  __builtin_amdgcn_global_load_lds(
      (const __attribute__((address_space(1))) unsigned int*)g,
      (__attribute__((address_space(3))) unsigned int*)l,
      16, 0, 0);
}

__device__ __forceinline__ u32 pkh(f16 a, f16 b) {
  union { f16 h[2]; u32 u; } x; x.h[0] = a; x.h[1] = b; return x.u;
}

// ---------------------------------------------------------------- convert ---
// blocks 0..8191: f32->f16 conversion.  blocks 8192..8193: per-batch padding
// length (dual-layout bool detector), written to lens_out[b].
__global__ __launch_bounds__(256) void convert_all(
    const float* __restrict__ q, const float* __restrict__ k, const float* __restrict__ v,
    const float* __restrict__ wq, const float* __restrict__ wk, const float* __restrict__ wv,
    const float* __restrict__ wo, const void* __restrict__ kpm_raw,
    f16* __restrict__ xh, f16* __restrict__ wh, int* __restrict__ lens_out) {
  int bid = blockIdx.x;
  if (bid >= 8192) {                // padding length for batch b
    int b = bid - 8192;
    __shared__ int s_c8, s_c32;
    if (threadIdx.x == 0) { s_c8 = 0; s_c32 = 0; }
    __syncthreads();
    int tid = threadIdx.x, lane = tid & 63;
    {
      const unsigned char* k8 = (const unsigned char*)kpm_raw + (long)b * T_;
      int cnt = 0;
      for (int j = tid; j < T_; j += 256) cnt += (k8[j] == 0) ? 1 : 0;
#pragma unroll
      for (int off = 1; off < 64; off <<= 1) cnt += __shfl_xor(cnt, off);
      if (lane == 0) atomicAdd(&s_c8, cnt);
    }
    {
      const int* k32 = (const int*)kpm_raw + (long)b * T_;
      int cnt = 0;
      for (int j = tid; j < T_; j += 256) cnt += (k32[j] == 0) ? 1 : 0;
#pragma unroll
      for (int off = 1; off < 64; off <<= 1) cnt += __shfl_xor(cnt, off);
      if (lane == 0) atomicAdd(&s_c32, cnt);
    }
    __syncthreads();
    if (tid == 0) lens_out[b] = (s_c8 == T_) ? s_c32 : s_c8;
    return;
  }
  const float* src;
  f16* dst;
  long base;
  if (bid < 6144) {                 // q,k,v : 3 x 4194304 elems, 2048 blocks each
    int r = bid >> 11;
    src = (r == 0) ? q : (r == 1) ? k : v;
    dst = xh + (long)r * 4194304;
    base = (long)(bid & 2047) * 2048;
  } else {                          // Wq,Wk,Wv,Wo : 4 x 1048576 elems, 512 blocks each
    int r = (bid - 6144) >> 9;
    src = (r == 0) ? wq : (r == 1) ? wk : (r == 2) ? wv : wo;
    dst = wh + (long)r * 1048576;
    base = (long)((bid - 6144) & 511) * 2048;
  }
  long e = base + (long)threadIdx.x * 8;
  const float4* s4 = (const float4*)(src + e);
  float4 f0 = s4[0], f1 = s4[1];
  f16x8 o;
  o[0] = (f16)f0.x; o[1] = (f16)f0.y; o[2] = (f16)f0.z; o[3] = (f16)f0.w;
  o[4] = (f16)f1.x; o[5] = (f16)f1.y; o[6] = (f16)f1.z; o[7] = (f16)f1.w;
  *(f16x8*)(dst + e) = o;
}

// ------------------------------------------------------------------- GEMM ---
// C = A(MxK) * W(NxK)^T.  M=4096, N=K=1024 for every GEMM in this problem.
// 2-phase double-buffered LDS pipeline (one barrier per K-step) + XCD swizzle.
// modes: 0 -> Qh (f16, *0.125)   1 -> Kh (f16)
//        2 -> Vt (f16, transposed per head [b,h,dh,t])   3 -> f32 out
__global__ __launch_bounds__(256) void gemm_k(
    const f16* __restrict__ Abase, const f16* __restrict__ Wbase,
    f16* __restrict__ Qb, f16* __restrict__ Kb, f16* __restrict__ Vt,
    float* __restrict__ Co, int which) {
  __shared__ __align__(16) f16 As[2][128][32];
  __shared__ __align__(16) f16 Bs[2][128][32];
  const int K = 1024, N = 1024;

  // XCD-aware chunked swizzle: 8 x-consecutive blocks (sharing an A panel)
  // land on ONE XCD. nwg = 768 or 256, both divisible by 8 -> bijective.
  int gx = gridDim.x, gy = gridDim.y;
  int nwg = gx * gy * gridDim.z;
  int bid = blockIdx.x + gx * (blockIdx.y + gy * blockIdx.z);
  int cpx = nwg >> 3;
  int wg = (bid & 7) * cpx + (bid >> 3);
  int bz = wg / (gx * gy);
  int rem = wg - bz * gx * gy;
  int by = rem / gx, bx = rem - by * gx;

  int mode;
  const f16 *A, *W;
  if (which) { mode = 3; A = Abase; W = Wbase; }
  else {
    mode = bz;
    A = Abase + (long)bz * 4194304;
    W = Wbase + (long)bz * 1048576;
  }
  int m0 = by * 128, n0 = bx * 128;
  int tid = threadIdx.x, lane = tid & 63, w = tid >> 6;
  int wm = w >> 1, wn = w & 1;

  int srow = w * 16 + (lane >> 2);
  int scol = (lane & 3) * 8;
  const f16* pa = A + (long)(m0 + srow) * K + scol;
  const f16* pb = W + (long)(n0 + srow) * K + scol;

  f32x4 acc[4][4] = {};
  int row = lane & 15, kq = (lane >> 4) * 8;

  auto STAGE = [&](int k0, int bsel) {
    async_ld16(pa + k0,          &As[bsel][srow][scol]);
    async_ld16(pa + 64 * K + k0, &As[bsel][64 + srow][scol]);
    async_ld16(pb + k0,          &Bs[bsel][srow][scol]);
    async_ld16(pb + 64 * K + k0, &Bs[bsel][64 + srow][scol]);
  };

  STAGE(0, 0);
  asm volatile("s_waitcnt vmcnt(0)" ::: "memory");
  __builtin_amdgcn_s_barrier();

  int cur = 0;
  for (int k0 = 0; k0 < K; k0 += 32) {
    if (k0 + 32 < K) STAGE(k0 + 32, cur ^ 1);
    f16x8 af[4], bfr[4];
#pragma unroll
    for (int m = 0; m < 4; m++) af[m] = *(const f16x8*)&As[cur][wm * 64 + m * 16 + row][kq];
#pragma unroll
    for (int n = 0; n < 4; n++) bfr[n] = *(const f16x8*)&Bs[cur][wn * 64 + n * 16 + row][kq];
#pragma unroll
    for (int m = 0; m < 4; m++)
#pragma unroll
      for (int n = 0; n < 4; n++)
        acc[m][n] = __builtin_amdgcn_mfma_f32_16x16x32_f16(af[m], bfr[n], acc[m][n], 0, 0, 0);
    asm volatile("s_waitcnt vmcnt(0)" ::: "memory");
    __builtin_amdgcn_s_barrier();
    cur ^= 1;
  }

  int r0 = (lane >> 4) * 4;
#pragma unroll
  for (int m = 0; m < 4; m++) {
    int gmb = m0 + wm * 64 + m * 16 + r0;
#pragma unroll
    for (int n = 0; n < 4; n++) {
      int gn = n0 + wn * 64 + n * 16 + row;
      if (mode == 0) {
#pragma unroll
        for (int i = 0; i < 4; i++)
          Qb[(long)(gmb + i) * N + gn] = (f16)(acc[m][n][i] * 0.125f);
      } else if (mode == 1) {
#pragma unroll
        for (int i = 0; i < 4; i++)
          Kb[(long)(gmb + i) * N + gn] = (f16)acc[m][n][i];
      } else if (mode == 2) {
        int b = gmb >> 11;
        int t = gmb & 2047;
        int h = gn >> 6, dh = gn & 63;
        f16x4 pk;
#pragma unroll
        for (int i = 0; i < 4; i++) pk[i] = (f16)acc[m][n][i];
        *(f16x4*)&Vt[(long)((b * 16 + h) * 64 + dh) * 2048 + t] = pk;
      } else {
#pragma unroll
        for (int i = 0; i < 4; i++)
          Co[(long)(gmb + i) * N + gn] = acc[m][n][i];
      }
    }
  }
}

// -------------------------------------------------------------- attention ---
// LDS-staged flash attention. Block = 4 waves = 128 q-rows (wave w owns 32).
// K[64][64] and V^T[64][64] tiles double-buffered in LDS, staged with
// global_load_lds (linear dest, XOR-swizzled global source so swizzled
// ds_read_b128 fragment reads are bank-conflict-free).
__global__ __launch_bounds__(256) void attn_k(
    const f16* __restrict__ Q, const f16* __restrict__ Kp,
    const f16* __restrict__ Vt, const int* __restrict__ Lens,
    f16* __restrict__ Ao) {
  __shared__ __align__(16) f16 Kl[2][4096];   // [buf][row*64 + chunk-swizzled]
  __shared__ __align__(16) f16 Vl[2][4096];   // [buf][dh*64 + chunk-swizzled]

  int tid = threadIdx.x, lane = tid & 63, w = tid >> 6;
  int qm = (gridDim.x - 1) - blockIdx.x;   // longest-first
  int bh = blockIdx.y;
  int b = bh >> 4, h = bh & 15;
  int r31 = lane & 31, hi = lane >> 5, hi8 = hi * 8;

  int len = Lens[b];
  int q0 = qm * 128;
  int q0w = q0 + w * 32;
  int gq = q0w + r31;

  int blk_kmax = min(q0 + 128, len);       // block-level visible keys
  int wav_kmax = min(q0w + 32, len);       // this wave's visible keys
  int NT = (blk_kmax + 63) >> 6;           // block-uniform tile count

  const f16* Qh = Q  + (long)b * T_ * D_ + h * 64;
  const f16* Kh = Kp + (long)b * T_ * D_ + h * 64;
  const f16* Vh = Vt + (long)(b * 16 + h) * 64 * T_;

  // stage-source constants: thread covers rows srow, srow+8 (shot s), chunk sc
  int srow = w * 16 + (lane >> 3);
  int sc8  = ((lane & 7) ^ ((lane >> 3) & 7)) * 8;   // swizzled 16B-chunk, f16 elems
  int ldst = w * 1024 + lane * 8;                    // f16 elems; +512 for shot 1

  // reader swizzled chunk offsets (constant per lane): logical chunk 2t+hi
  int coff[4];
#pragma unroll
  for (int t = 0; t < 4; t++) coff[t] = ((2 * t + hi) ^ (r31 & 7)) * 8;

  auto STAGE = [&](int t, int bsel) {
    int kb = t * 64;
#pragma unroll
    for (int s = 0; s < 2; s++) {
      int row = srow + s * 8;
      async_ld16(Kh + (long)(kb + row) * D_ + sc8, &Kl[bsel][ldst + s * 512]);
      async_ld16(Vh + (long)row * T_ + kb + sc8,   &Vl[bsel][ldst + s * 512]);
    }
  };

  // Q fragments: lane holds Q[gq][16t + hi*8 .. +8]
  STAGE(0, 0);
  f16x8 qf[4];
#pragma unroll
  for (int t = 0; t < 4; t++)
    qf[t] = *(const f16x8*)(Qh + (long)gq * D_ + t * 16 + hi8);

  f32x16 o0 = {}, o1 = {};       // O^T partials: dh-tiles 0 (0..31), 1 (32..63)
  float mrun = -1e30f, lrun = 0.f;

  asm volatile("s_waitcnt vmcnt(0)" ::: "memory");
  __syncthreads();

  for (int t = 0; t < NT; t++) {
    int cur = t & 1;
    if (t + 1 < NT) STAGE(t + 1, cur ^ 1);

    int kb = t * 64;
    if (kb < wav_kmax) {
      f32x16 s0 = {}, s1 = {};
#pragma unroll
      for (int tq = 0; tq < 4; tq++) {
        f16x8 k0 = *(const f16x8*)&Kl[cur][(r31)      * 64 + coff[tq]];
        f16x8 k1 = *(const f16x8*)&Kl[cur][(32 + r31) * 64 + coff[tq]];
        s0 = __builtin_amdgcn_mfma_f32_32x32x16_f16(k0, qf[tq], s0, 0, 0, 0);
        s1 = __builtin_amdgcn_mfma_f32_32x32x16_f16(k1, qf[tq], s1, 0, 0, 0);
      }

      bool needmask = (kb + 64 > q0w) || (kb + 64 > len);
      float sv[32];
      if (needmask) {
#pragma unroll
        for (int r = 0; r < 16; r++) {
          int pat = (r & 3) + 8 * (r >> 2) + 4 * hi;
          int gk0 = kb + pat, gk1 = kb + 32 + pat;
          sv[r]      = (gk0 > gq || gk0 >= len) ? -1e30f : s0[r];
          sv[16 + r] = (gk1 > gq || gk1 >= len) ? -1e30f : s1[r];
        }
      } else {
#pragma unroll
        for (int r = 0; r < 16; r++) { sv[r] = s0[r]; sv[16 + r] = s1[r]; }
      }

      float mx = fmaxf(sv[0], sv[1]);
#pragma unroll
      for (int r = 2; r < 32; r++) mx = fmaxf(mx, sv[r]);
      mx = fmaxf(mx, __shfl_xor(mx, 32));

      float mnew = fmaxf(mrun, mx);
      float sf = __expf(mrun - mnew);
      mrun = mnew;

      f16 p16[32];
      float ps[4] = {0.f, 0.f, 0.f, 0.f};
#pragma unroll
      for (int r = 0; r < 32; r++) {
        float p = __expf(sv[r] - mnew);
        f16 hp = (f16)p;
        p16[r] = hp;
        ps[r & 3] += (float)hp;    // denominator from the SAME rounded weights
      }
      float psum = (ps[0] + ps[1]) + (ps[2] + ps[3]);
      lrun = lrun * sf + psum + __shfl_xor(psum, 32);

      o0 *= sf;
      o1 *= sf;

      u32 A0 = pkh(p16[0],  p16[1]),  A1 = pkh(p16[2],  p16[3]);
      u32 B0 = pkh(p16[4],  p16[5]),  B1 = pkh(p16[6],  p16[7]);
      u32 C0 = pkh(p16[8],  p16[9]),  C1 = pkh(p16[10], p16[11]);
      u32 D0 = pkh(p16[12], p16[13]), D1 = pkh(p16[14], p16[15]);
      u32 E0 = pkh(p16[16], p16[17]), E1 = pkh(p16[18], p16[19]);
      u32 F0 = pkh(p16[20], p16[21]), F1 = pkh(p16[22], p16[23]);
      u32 G0 = pkh(p16[24], p16[25]), G1 = pkh(p16[26], p16[27]);
      u32 H0 = pkh(p16[28], p16[29]), H1 = pkh(p16[30], p16[31]);
      u32 sA0 = __shfl_xor(A0, 32), sA1 = __shfl_xor(A1, 32);
      u32 sB0 = __shfl_xor(B0, 32), sB1 = __shfl_xor(B1, 32);
      u32 sC0 = __shfl_xor(C0, 32), sC1 = __shfl_xor(C1, 32);
      u32 sD0 = __shfl_xor(D0, 32), sD1 = __shfl_xor(D1, 32);
      u32 sE0 = __shfl_xor(E0, 32), sE1 = __shfl_xor(E1, 32);
      u32 sF0 = __shfl_xor(F0, 32), sF1 = __shfl_xor(F1, 32);
      u32 sG0 = __shfl_xor(G0, 32), sG1 = __shfl_xor(G1, 32);
      u32 sH0 = __shfl_xor(H0, 32), sH1 = __shfl_xor(H1, 32);

      union { u32 w[4]; f16x8 v; } f00, f01, f10, f11;
      f00.w[0] = hi ? sB0 : A0;  f00.w[1] = hi ? sB1 : A1;
      f00.w[2] = hi ? B0 : sA0;  f00.w[3] = hi ? B1 : sA1;
      f01.w[0] = hi ? sD0 : C0;  f01.w[1] = hi ? sD1 : C1;
      f01.w[2] = hi ? D0 : sC0;  f01.w[3] = hi ? D1 : sC1;
      f10.w[0] = hi ? sF0 : E0;  f10.w[1] = hi ? sF1 : E1;
      f10.w[2] = hi ? F0 : sE0;  f10.w[3] = hi ? F1 : sE1;
      f11.w[0] = hi ? sH0 : G0;  f11.w[1] = hi ? sH1 : G1;
      f11.w[2] = hi ? H0 : sG0;  f11.w[3] = hi ? H1 : sG1;

      f16x8 v00 = *(const f16x8*)&Vl[cur][(r31)      * 64 + coff[0]];
      f16x8 v01 = *(const f16x8*)&Vl[cur][(r31)      * 64 + coff[1]];
      f16x8 v02 = *(const f16x8*)&Vl[cur][(r31)      * 64 + coff[2]];
      f16x8 v03 = *(const f16x8*)&Vl[cur][(r31)      * 64 + coff[3]];
      f16x8 v10 = *(const f16x8*)&Vl[cur][(32 + r31) * 64 + coff[0]];
      f16x8 v11 = *(const f16x8*)&Vl[cur][(32 + r31) * 64 + coff[1]];
      f16x8 v12 = *(const f16x8*)&Vl[cur][(32 + r31) * 64 + coff[2]];
      f16x8 v13 = *(const f16x8*)&Vl[cur][(32 + r31) * 64 + coff[3]];

      o0 = __builtin_amdgcn_mfma_f32_32x32x16_f16(v00, f00.v, o0, 0, 0, 0);
      o0 = __builtin_amdgcn_mfma_f32_32x32x16_f16(v01, f01.v, o0, 0, 0, 0);
      o0 = __builtin_amdgcn_mfma_f32_32x32x16_f16(v02, f10.v, o0, 0, 0, 0);
      o0 = __builtin_amdgcn_mfma_f32_32x32x16_f16(v03, f11.v, o0, 0, 0, 0);
      o1 = __builtin_amdgcn_mfma_f32_32x32x16_f16(v10, f00.v, o1, 0, 0, 0);
      o1 = __builtin_amdgcn_mfma_f32_32x32x16_f16(v11, f01.v, o1, 0, 0, 0);
      o1 = __builtin_amdgcn_mfma_f32_32x32x16_f16(v12, f10.v, o1, 0, 0, 0);
      o1 = __builtin_amdgcn_mfma_f32_32x32x16_f16(v13, f11.v, o1, 0, 0, 0);
    }

    asm volatile("s_waitcnt vmcnt(0)" ::: "memory");
    __syncthreads();
  }

  float linv = 1.f / lrun;
  f16* Aob = Ao + (long)(b * T_ + gq) * D_ + h * 64 + 4 * hi;
#pragma unroll
  for (int g = 0; g < 4; g++) {
    f16x4 s0, s1;
#pragma unroll
    for (int i = 0; i < 4; i++) {
      s0[i] = (f16)(o0[g * 4 + i] * linv);
      s1[i] = (f16)(o1[g * 4 + i] * linv);
    }
    *(f16x4*)(Aob + 8 * g)      = s0;
    *(f16x4*)(Aob + 32 + 8 * g) = s1;
  }
}

// ------------------------------------------------------------------ launch ---
extern "C" void kernel_launch(void* const* d_in, const int* in_sizes, int n_in,
                              void* d_out, int out_size, void* d_ws, size_t ws_size,
                              hipStream_t stream) {
  const float* q  = (const float*)d_in[0];
  const float* k  = (const float*)d_in[1];
  const float* v  = (const float*)d_in[2];
  // d_in[3] = causal mask (analytic, unused)
  const void* kpm = d_in[4];
  const float* wq = (const float*)d_in[5];
  const float* wk = (const float*)d_in[6];
  const float* wv = (const float*)d_in[7];
  const float* wo = (const float*)d_in[8];

  char* ws = (char*)d_ws;
  f16* Xh = (f16*)(ws);                     // 3 * 8 MB
  f16* Wh = (f16*)(ws + 25165824);          // 4 * 2 MB
  f16* Qb = (f16*)(ws + 33554432);          // 8 MB
  f16* Kb = (f16*)(ws + 41943040);          // 8 MB
  f16* Vt = (f16*)(ws + 50331648);          // 8 MB
  f16* Ao = (f16*)(ws + 58720256);          // 8 MB  (total 64 MB)
  // Lens scratch: first 2 ints of d_out — read by attn, then fully
  // overwritten by the final GEMM.
  int* Lens = (int*)d_out;

  convert_all<<<8194, 256, 0, stream>>>(q, k, v, wq, wk, wv, wo, kpm, Xh, Wh, Lens);

  gemm_k<<<dim3(8, 32, 3), 256, 0, stream>>>(Xh, Wh, Qb, Kb, Vt, nullptr, 0);

  attn_k<<<dim3(T_ / 128, B_ * H_), 256, 0, stream>>>(Qb, Kb, Vt, Lens, Ao);

  gemm_k<<<dim3(8, 32, 1), 256, 0, stream>>>(Ao, Wh + 3 * 1048576, nullptr, nullptr,
                                             nullptr, (float*)d_out, 1);
}